// Round 21
// baseline (379.698 us; speedup 1.0000x reference)
//
#include <hip/hip_runtime.h>

typedef __attribute__((ext_vector_type(8))) short short8;
typedef __attribute__((ext_vector_type(4))) float f32x4;
typedef __attribute__((ext_vector_type(4))) unsigned short us4;
typedef __attribute__((ext_vector_type(4))) float float4v;

#define GLB_PTR(p) ((const __attribute__((address_space(1))) void*)(p))
#define LDS_PTR(p) ((__attribute__((address_space(3))) void*)(p))

__device__ __forceinline__ unsigned short f2bf(float f) {
  unsigned int u = __float_as_uint(f);
  u += 0x7FFF + ((u >> 16) & 1);   // round-to-nearest-even
  return (unsigned short)(u >> 16);
}

// ---------------- fp32 -> bf16 converts (EHS + 4 weights; HS conversion fused into gemm_q) ----
__global__ void cvt_all(const float* __restrict__ i1,
                        const float* __restrict__ i2, const float* __restrict__ i3,
                        const float* __restrict__ i4, const float* __restrict__ i5,
                        unsigned short* __restrict__ o1,
                        unsigned short* __restrict__ o2, unsigned short* __restrict__ o3,
                        unsigned short* __restrict__ o4, unsigned short* __restrict__ o5) {
  constexpr int N1 = 616 * 1536 / 4, NW = 1536 * 1536 / 4;
  constexpr int TOT = N1 + 4 * NW;
  int i = blockIdx.x * blockDim.x + threadIdx.x;
  const int stride = gridDim.x * blockDim.x;
  for (; i < TOT; i += stride) {
    const float* in; unsigned short* out; int j = i;
    if (j < N1) { in = i1; out = o1; }
    else {
      j -= N1;
      const int t = j / NW; j -= t * NW;
      in  = t == 0 ? i2 : t == 1 ? i3 : t == 2 ? i4 : i5;
      out = t == 0 ? o2 : t == 1 ? o3 : t == 2 ? o4 : o5;
    }
    float4v v = *(const float4v*)(in + (size_t)j * 4);
    us4 o;
    o[0] = f2bf(v[0]); o[1] = f2bf(v[1]); o[2] = f2bf(v[2]); o[3] = f2bf(v[3]);
    *(us4*)(out + (size_t)j * 4) = o;
  }
}

// ---------------- Q-projection GEMM with FUSED fp32->bf16 A-conversion ----------------
// C[16384,1536] = bf16(HS fp32) * Wqb^T. 256x128 tile, BK=32, 8 waves (4M x 2N),
// wave tile 64x64 (acc[4][4]). DEPTH-2 48 KB LDS (3 blocks/CU; grid 768 = exact fill).
// A reg-staged: fp32 global_load_dwordx4 x4 -> f2bf pack -> ds_write_b128 (swizzled layout,
// byte-identical to r17's gload_lds layout). B via global_load_lds (unchanged).
// Sync per iter: frag-reads -> lgkm(0) [also drains prev cvt ds_writes] -> barrier ->
// vmcnt(0) [drains A(kt+2) regs + B(kt+1), both issued a full iter earlier -> ~free] ->
// cvtwrite(kt+2) + issueA(kt+3) + stageB(kt+2) -> MFMA -> barrier.
// Swizzle (0-conflict, r17-verified): LDS[row][g] holds global granule g^((row>>1)&3).
__device__ __forceinline__ void gemm_q_body(
    const float* __restrict__ A,             // HS fp32 [16384,1536]
    const unsigned short* __restrict__ B,    // Wqb bf16 [1536,1536]
    unsigned short* __restrict__ Cb,         // Qb bf16
    unsigned short* smem, int bid, int tid) {
  constexpr int K = 1536, N = 1536, BK = 32, NKT = K / BK;  // 48 K-tiles
  unsigned short* As = smem;             // 2 x 256x32 elems
  unsigned short* Bs = smem + 2 * 8192;  // 2 x 128x32 elems

  // XCD-chunked swizzle: 768 blocks -> 96/XCD = 8 m-tiles x 12 n-tiles, n fastest
  const int xcd = bid & 7, idx = bid >> 3;
  const int m0 = (xcd * 8 + idx / 12) * 256;
  const int n0 = (idx % 12) * 128;

  const int w = tid >> 6, l = tid & 63, lr = l & 15, lg = l >> 4;
  const int wr = w >> 1, wc = w & 1;               // 4M x 2N wave grid, wave tile 64x64
  const int ga = lg ^ ((lr >> 1) & 3);             // 0-conflict read granule

  const int srow = w * 16 + (l >> 2);              // staging row 0..127 (+128 for chunk 1)
  const int sg = (l & 3) ^ ((l >> 3) & 3);         // source granule: g ^ ((row>>1)&3)
  const float* aSrc0 = A + (size_t)(m0 + srow) * K + sg * 8;
  const float* aSrc1 = A + (size_t)(m0 + 128 + srow) * K + sg * 8;
  const unsigned short* bSrc = B + (size_t)(n0 + srow) * K + sg * 8;

  f32x4 acc[4][4] = {};
  float4v aR[2][2];                                // 16 VGPR in-flight fp32 A

  auto issueA = [&](int kt) {                      // 4 global dwordx4 loads -> regs
    if (kt >= NKT) return;
    const int k0 = kt * BK;
    aR[0][0] = *(const float4v*)(aSrc0 + k0);
    aR[0][1] = *(const float4v*)(aSrc0 + k0 + 4);
    aR[1][0] = *(const float4v*)(aSrc1 + k0);
    aR[1][1] = *(const float4v*)(aSrc1 + k0 + 4);
  };
  auto cvtwrite = [&](int buf) {                   // pack + 2 ds_write_b128 (linear dest)
#pragma unroll
    for (int i = 0; i < 2; ++i) {
      short8 v;
#pragma unroll
      for (int e = 0; e < 4; ++e) {
        v[e]     = (short)f2bf(aR[i][0][e]);
        v[e + 4] = (short)f2bf(aR[i][1][e]);
      }
      *(short8*)(&As[buf * 8192 + i * 4096 + w * 512 + l * 8]) = v;
    }
  };
  auto stageB = [&](int buf, int kt) {             // 1 gload_lds/wave
    if (kt >= NKT) return;
    __builtin_amdgcn_global_load_lds(GLB_PTR(bSrc + kt * BK),
        LDS_PTR(Bs + buf * 4096 + w * 512), 16, 0, 0);
  };
  auto loadfrags = [&](int buf, short8* af, short8* bfv) {
#pragma unroll
    for (int i = 0; i < 4; ++i)
      af[i] = *(const short8*)(&As[buf * 8192 + (wr * 64 + i * 16 + lr) * 32 + ga * 8]);
#pragma unroll
    for (int j = 0; j < 4; ++j)
      bfv[j] = *(const short8*)(&Bs[buf * 4096 + (wc * 64 + j * 16 + lr) * 32 + ga * 8]);
  };

  // prologue: tiles 0,1 into LDS (A converted in-reg), A(2) loads in flight, B(0,1) drained
  issueA(0); stageB(0, 0);
  asm volatile("s_waitcnt vmcnt(0)" ::: "memory");
  cvtwrite(0);
  issueA(1); stageB(1, 1);
  asm volatile("s_waitcnt vmcnt(0)" ::: "memory");
  cvtwrite(1);
  issueA(2);
  asm volatile("s_waitcnt lgkmcnt(0)" ::: "memory");   // ds_writes drained
  __builtin_amdgcn_s_barrier();                        // tiles 0,1 visible everywhere

  for (int kt = 0; kt < NKT; ++kt) {
    short8 af[4], bfv[4];
    loadfrags(kt & 1, af, bfv);
    asm volatile("s_waitcnt lgkmcnt(0)" ::: "memory"); // frags in regs (+ prev writes drained)
    __builtin_amdgcn_sched_barrier(0);
    __builtin_amdgcn_s_barrier();                      // all waves done reading buf kt&1
    __builtin_amdgcn_sched_barrier(0);
    asm volatile("s_waitcnt vmcnt(0)" ::: "memory");   // A(kt+2) regs + B(kt+1) landed (~free)
    __builtin_amdgcn_sched_barrier(0);
    if (kt + 2 < NKT) cvtwrite(kt & 1);                // tile kt+2 -> freed buffer
    issueA(kt + 3);
    stageB(kt & 1, kt + 2);
    __builtin_amdgcn_s_setprio(1);
#pragma unroll
    for (int i = 0; i < 4; ++i)
#pragma unroll
      for (int j = 0; j < 4; ++j)
        acc[i][j] = __builtin_amdgcn_mfma_f32_16x16x32_bf16(af[i], bfv[j], acc[i][j], 0, 0, 0);
    __builtin_amdgcn_s_setprio(0);
    __builtin_amdgcn_s_barrier();                      // end-of-iter rendezvous
  }

#pragma unroll
  for (int i = 0; i < 4; ++i) {
    const int rb = m0 + wr * 64 + i * 16 + lg * 4;
#pragma unroll
    for (int j = 0; j < 4; ++j) {
      const int col = n0 + wc * 64 + j * 16 + lr;
#pragma unroll
      for (int r = 0; r < 4; ++r)
        Cb[(size_t)(rb + r) * N + col] = f2bf(acc[i][j][r]);
    }
  }
}

// ---------------- O-projection GEMM body (r18 measured-best, unchanged): ----------------
// 256x128, BK=32, 4 waves (2M x 2N), wave tile 128x64 (acc[8][4]). DEPTH-2 48 KB LDS,
// 0-conflict swizzle. C fp32 = acc + bias[n] + resid[m,n].
__device__ __forceinline__ void gemm_o_body(
    const unsigned short* __restrict__ A,
    const unsigned short* __restrict__ B,
    float* __restrict__ Cf,
    const float* __restrict__ bias,
    const float* __restrict__ resid,
    unsigned short* smem, int bid, int tid) {
  constexpr int K = 1536, N = 1536, BK = 32, NKT = K / BK;
  unsigned short* As = smem;             // 2 x 256x32
  unsigned short* Bs = smem + 2 * 8192;  // 2 x 128x32

  const int xcd = bid & 7, idx = bid >> 3;
  const int m0 = (xcd * 8 + idx / 12) * 256;
  const int n0 = (idx % 12) * 128;

  const int w = tid >> 6, l = tid & 63, lr = l & 15, lg = l >> 4;
  const int wr = w >> 1, wc = w & 1;
  const int ga = lg ^ ((lr >> 1) & 3);

  const int srow = tid >> 2;
  const int sg = (l & 3) ^ ((l >> 3) & 3);
  const unsigned short* aSrc = A + (size_t)(m0 + srow) * K + sg * 8;
  const unsigned short* bSrc = B + (size_t)(n0 + srow) * K + sg * 8;

  f32x4 acc[8][4] = {};

  auto stage = [&](int buf, int kt) {
    const int k0 = kt * BK;
    unsigned short* AsW = As + buf * 8192 + w * 512;
    unsigned short* BsW = Bs + buf * 4096 + w * 512;
#pragma unroll
    for (int i = 0; i < 4; ++i)
      __builtin_amdgcn_global_load_lds(GLB_PTR(aSrc + (size_t)(i * 64) * K + k0), LDS_PTR(AsW + i * 2048), 16, 0, 0);
#pragma unroll
    for (int i = 0; i < 2; ++i)
      __builtin_amdgcn_global_load_lds(GLB_PTR(bSrc + (size_t)(i * 64) * K + k0), LDS_PTR(BsW + i * 2048), 16, 0, 0);
  };

  auto loadfrags = [&](int buf, short8* af, short8* bfv) {
    const unsigned short* Asb = As + buf * 8192;
    const unsigned short* Bsb = Bs + buf * 4096;
#pragma unroll
    for (int i = 0; i < 8; ++i)
      af[i] = *(const short8*)(Asb + (wr * 128 + i * 16 + lr) * 32 + ga * 8);
#pragma unroll
    for (int j = 0; j < 4; ++j)
      bfv[j] = *(const short8*)(Bsb + (wc * 64 + j * 16 + lr) * 32 + ga * 8);
  };

  stage(0, 0); stage(1, 1);

  for (int kt = 0; kt < NKT; ++kt) {
    if (kt < NKT - 1) asm volatile("s_waitcnt vmcnt(6)" ::: "memory");
    else              asm volatile("s_waitcnt vmcnt(0)" ::: "memory");
    __builtin_amdgcn_s_barrier();
    __builtin_amdgcn_sched_barrier(0);
    short8 af[8], bfv[4];
    loadfrags(kt & 1, af, bfv);
    asm volatile("s_waitcnt lgkmcnt(0)" ::: "memory");
    __builtin_amdgcn_sched_barrier(0);
    __builtin_amdgcn_s_barrier();
    __builtin_amdgcn_sched_barrier(0);
    if (kt + 2 < NKT) stage(kt & 1, kt + 2);
    __builtin_amdgcn_s_setprio(1);
#pragma unroll
    for (int i = 0; i < 8; ++i)
#pragma unroll
      for (int j = 0; j < 4; ++j)
        acc[i][j] = __builtin_amdgcn_mfma_f32_16x16x32_bf16(af[i], bfv[j], acc[i][j], 0, 0, 0);
    __builtin_amdgcn_s_setprio(0);
  }

#pragma unroll
  for (int i = 0; i < 8; ++i) {
    const int rb = m0 + wr * 128 + i * 16 + lg * 4;
#pragma unroll
    for (int j = 0; j < 4; ++j) {
      const int col = n0 + wc * 64 + j * 16 + lr;
#pragma unroll
      for (int r = 0; r < 4; ++r) {
        size_t o = (size_t)(rb + r) * N + col;
        Cf[o] = acc[i][j][r] + bias[col] + resid[o];
      }
    }
  }
}

// ---------------- K+V projection body (waves 0-3 active; waves 4-7 barrier-only) ----------------
__device__ __forceinline__ void gemm_kv_body(
    const unsigned short* __restrict__ A,    // EHSb [616,1536]
    const unsigned short* __restrict__ Bk,
    const unsigned short* __restrict__ Bv,
    unsigned short* __restrict__ Ck,
    unsigned short* __restrict__ Vt,
    unsigned short* smem, int by, int tid) {
  constexpr int K = 1536, N = 1536, Mc = 615;
  unsigned short* As = smem;
  unsigned short* Bs = smem + 4096;
  const int bx = by % 5, yy = by / 5;
  const unsigned short* B = yy < 12 ? Bk : Bv;
  const int m0 = bx * 128, n0 = (yy % 12) * 128;
  const bool act = tid < 256;
  const int t = tid;
  const int w = t >> 6, l = t & 63, lr = l & 15, lg = l >> 4;
  const int wr = w >> 1, wc = w & 1;
  const int srow = t >> 2, scol = (t & 3) * 8;

  f32x4 acc[4][4] = {};
  unsigned short* AsW = As + w * 512;
  unsigned short* BsW = Bs + w * 512;
  long ar0 = m0 + srow;       if (ar0 > Mc) ar0 = Mc;
  long ar1 = m0 + srow + 64;  if (ar1 > Mc) ar1 = Mc;

  for (int k0 = 0; k0 < K; k0 += 32) {
    if (act) {
      __builtin_amdgcn_global_load_lds(GLB_PTR(A + ar0 * (long)K + k0 + scol), LDS_PTR(AsW),        16, 0, 0);
      __builtin_amdgcn_global_load_lds(GLB_PTR(A + ar1 * (long)K + k0 + scol), LDS_PTR(AsW + 2048), 16, 0, 0);
      __builtin_amdgcn_global_load_lds(GLB_PTR(B + (long)(n0 + srow) * K + k0 + scol),      LDS_PTR(BsW),        16, 0, 0);
      __builtin_amdgcn_global_load_lds(GLB_PTR(B + (long)(n0 + srow + 64) * K + k0 + scol), LDS_PTR(BsW + 2048), 16, 0, 0);
    }
    __syncthreads();
    if (act) {
      short8 af[4], bfv[4];
#pragma unroll
      for (int i = 0; i < 4; ++i) {
        af[i]  = *(const short8*)(As + (wr * 64 + i * 16 + lr) * 32 + lg * 8);
        bfv[i] = *(const short8*)(Bs + (wc * 64 + i * 16 + lr) * 32 + lg * 8);
      }
#pragma unroll
      for (int i = 0; i < 4; ++i)
#pragma unroll
        for (int j = 0; j < 4; ++j)
          acc[i][j] = __builtin_amdgcn_mfma_f32_16x16x32_bf16(af[i], bfv[j], acc[i][j], 0, 0, 0);
    }
    __syncthreads();
  }

  if (!act) return;
  if (yy < 12) {
#pragma unroll
    for (int i = 0; i < 4; ++i) {
      int rb = m0 + wr * 64 + i * 16 + lg * 4;
#pragma unroll
      for (int j = 0; j < 4; ++j) {
        int col = n0 + wc * 64 + j * 16 + lr;
#pragma unroll
        for (int r = 0; r < 4; ++r)
          Ck[(long)(rb + r) * N + col] = f2bf(acc[i][j][r]);
      }
    }
  } else {
#pragma unroll
    for (int i = 0; i < 4; ++i) {
      int rb = m0 + wr * 64 + i * 16 + lg * 4;
#pragma unroll
      for (int j = 0; j < 4; ++j) {
        int col = n0 + wc * 64 + j * 16 + lr;
        int hh = col >> 6, dd = col & 63;
#pragma unroll
        for (int r = 0; r < 4; ++r) {
          int m = rb + r;
          if (m < 616) {
            int c = (unsigned)m / 154u;
            int e = m - c * 154;
            Vt[((long)((c * 24 + hh) * 64 + dd)) * 160 + e] = f2bf(acc[i][j][r]);
          }
        }
      }
    }
  }
}

// ---------------- merged Q-projection (fused cvt) + K/V-projection launch ----------------
// blocks 0..767: Q GEMM (exactly one 3-blocks/CU fill); blocks 768..887: K/V projection (tail).
__global__ __launch_bounds__(512, 4) void gemm_q_kv(
    const float* __restrict__ HS, const unsigned short* __restrict__ Wqb,
    unsigned short* __restrict__ Qb,
    const unsigned short* __restrict__ EHSb, const unsigned short* __restrict__ Wkb,
    const unsigned short* __restrict__ Wvb,
    unsigned short* __restrict__ Ck, unsigned short* __restrict__ Vt) {
  __shared__ unsigned short smem[24576];   // 48 KB
  if (blockIdx.x < 768)
    gemm_q_body(HS, Wqb, Qb, smem, blockIdx.x, threadIdx.x);
  else
    gemm_kv_body(EHSb, Wkb, Wvb, Ck, Vt, smem, blockIdx.x - 768, threadIdx.x);
}

// ---------------- O-projection GEMM (+ bias + residual, fp32 out) ----------------
__global__ __launch_bounds__(256, 2) void gemm_o(
    const unsigned short* __restrict__ Ob, const unsigned short* __restrict__ Wob,
    float* __restrict__ Cf, const float* __restrict__ bias, const float* __restrict__ resid) {
  __shared__ unsigned short smem[24576];
  gemm_o_body(Ob, Wob, Cf, bias, resid, smem, blockIdx.x, threadIdx.x);
}

// ---------------- fused cross-component attention (r18 measured-best, unchanged) ----------------
__global__ __launch_bounds__(256) void attn_kernel(
    const unsigned short* __restrict__ Qb,   // [4*4096, 1536]
    const unsigned short* __restrict__ Kb,   // [640, 1536]; rows c*154+e (rows>=616 junk, masked)
    const unsigned short* __restrict__ Vt,   // [4][24][64][160]; e>=154 junk, masked via P
    const float* __restrict__ temp,
    unsigned short* __restrict__ Ob) {       // [4*4096, 1536]
  __shared__ unsigned short P[4][4][16][160];  // [wave][c][s][e] bf16 weights (wave-private)
  const int h = blockIdx.y, sb = blockIdx.x;
  const int t = threadIdx.x, w = t >> 6, l = t & 63, lr = l & 15, lg = l >> 4;
  const int s0 = sb * 64 + w * 16;
  const float sc = 1.0f / (temp[0] + 1e-8f);

  short8 qf[4][2];
#pragma unroll
  for (int c = 0; c < 4; ++c)
#pragma unroll
    for (int kt = 0; kt < 2; ++kt)
      qf[c][kt] = *(const short8*)(Qb + (long)(c * 4096 + s0 + lr) * 1536 + h * 64 + kt * 32 + lg * 8);

  short8 kA[4][2], kB[4][2];
  auto loadK = [&](int et, short8 (&k)[4][2]) {
#pragma unroll
    for (int c = 0; c < 4; ++c)
#pragma unroll
      for (int kt = 0; kt < 2; ++kt)
        k[c][kt] = *(const short8*)(Kb + (long)(c * 154 + et * 16 + lr) * 1536 + h * 64 + kt * 32 + lg * 8);
  };

  auto qk_step = [&](int et, short8 (&kc)[4][2], short8 (&kn)[4][2], bool pre) {
    if (pre) loadK(et + 1, kn);
    f32x4 sa[4] = {};
#pragma unroll
    for (int c = 0; c < 4; ++c)
#pragma unroll
      for (int kt = 0; kt < 2; ++kt)
        sa[c] = __builtin_amdgcn_mfma_f32_16x16x32_bf16(kc[c][kt], qf[c][kt], sa[c], 0, 0, 0);
    float wv[4][4];
#pragma unroll
    for (int r = 0; r < 4; ++r) {
      float e0 = __expf(sa[0][r] * sc), e1 = __expf(sa[1][r] * sc);
      float e2 = __expf(sa[2][r] * sc), e3 = __expf(sa[3][r] * sc);
      float inv = 1.0f / (e0 + e1 + e2 + e3);
      wv[0][r] = e0 * inv; wv[1][r] = e1 * inv; wv[2][r] = e2 * inv; wv[3][r] = e3 * inv;
    }
#pragma unroll
    for (int c = 0; c < 4; ++c) {
      us4 pk;
#pragma unroll
      for (int r = 0; r < 4; ++r)
        pk[r] = (et * 16 + lg * 4 + r < 154) ? f2bf(wv[c][r]) : (unsigned short)0;
      *(us4*)&P[w][c][lr][et * 16 + lg * 4] = pk;
    }
  };

  loadK(0, kA);
#pragma unroll
  for (int et = 0; et < 10; et += 2) {
    qk_step(et,     kA, kB, true);
    qk_step(et + 1, kB, kA, et + 1 < 9);
  }
  asm volatile("s_waitcnt lgkmcnt(0)" ::: "memory");
  __builtin_amdgcn_sched_barrier(0);

  short8 vA[4], vB[4];
  auto loadV = [&](int c, int ks, short8 (&v)[4]) {
#pragma unroll
    for (int nt = 0; nt < 4; ++nt)
      v[nt] = *(const short8*)(Vt + (long)((c * 24 + h) * 64 + nt * 16 + lr) * 160 + ks * 32 + lg * 8);
  };

  f32x4 o[4][4] = {};
  loadV(0, 0, vA);
#pragma unroll
  for (int p = 0; p < 10; ++p) {
    const int i0 = 2 * p, i1 = 2 * p + 1;
    const int c0 = i0 / 5, k0 = i0 % 5;
    const int c1 = i1 / 5, k1 = i1 % 5;
    loadV(c1, k1, vB);
    short8 pf0 = *(const short8*)&P[w][c0][lr][k0 * 32 + lg * 8];
#pragma unroll
    for (int nt = 0; nt < 4; ++nt)
      o[c0][nt] = __builtin_amdgcn_mfma_f32_16x16x32_bf16(pf0, vA[nt], o[c0][nt], 0, 0, 0);
    if (p < 9) loadV((i1 + 1) / 5, (i1 + 1) % 5, vA);
    short8 pf1 = *(const short8*)&P[w][c1][lr][k1 * 32 + lg * 8];
#pragma unroll
    for (int nt = 0; nt < 4; ++nt)
      o[c1][nt] = __builtin_amdgcn_mfma_f32_16x16x32_bf16(pf1, vB[nt], o[c1][nt], 0, 0, 0);
  }

  unsigned short* OS = &P[w][0][0][0];
#pragma unroll
  for (int c = 0; c < 4; ++c) {
#pragma unroll
    for (int nt = 0; nt < 4; ++nt)
#pragma unroll
      for (int r = 0; r < 4; ++r)
        OS[(lg * 4 + r) * 64 + nt * 16 + lr] = f2bf(o[c][nt][r]);
    asm volatile("s_waitcnt lgkmcnt(0)" ::: "memory");
    __builtin_amdgcn_sched_barrier(0);
#pragma unroll
    for (int p = 0; p < 2; ++p) {
      const int flat = p * 512 + l * 8;
      const int row = flat >> 6, col = flat & 63;
      short8 v = *(const short8*)(OS + flat);
      *(short8*)(Ob + (long)(c * 4096 + s0 + row) * 1536 + h * 64 + col) = v;
    }
  }
}

extern "C" void kernel_launch(void* const* d_in, const int* in_sizes, int n_in,
                              void* d_out, int out_size, void* d_ws, size_t ws_size,
                              hipStream_t stream) {
  (void)in_sizes; (void)n_in; (void)out_size; (void)ws_size;
  const float* HS  = (const float*)d_in[0];
  const float* EHS = (const float*)d_in[1];
  const float* TMP = (const float*)d_in[2];
  const float* Wq  = (const float*)d_in[3];
  const float* Wk  = (const float*)d_in[4];
  const float* Wv  = (const float*)d_in[5];
  const float* Wo  = (const float*)d_in[6];
  const float* bo  = (const float*)d_in[7];

  char* ws = (char*)d_ws;
  size_t off = 0;
  unsigned short* Ob   = (unsigned short*)(ws + off); off += (size_t)16384 * 1536 * 2;
  unsigned short* EHSb = (unsigned short*)(ws + off); off += (size_t)616 * 1536 * 2;
  unsigned short* Wqb  = (unsigned short*)(ws + off); off += (size_t)1536 * 1536 * 2;
  unsigned short* Wkb  = (unsigned short*)(ws + off); off += (size_t)1536 * 1536 * 2;
  unsigned short* Wvb  = (unsigned short*)(ws + off); off += (size_t)1536 * 1536 * 2;
  unsigned short* Wob  = (unsigned short*)(ws + off); off += (size_t)1536 * 1536 * 2;
  unsigned short* Kb   = (unsigned short*)(ws + off); off += (size_t)640 * 1536 * 2;
  unsigned short* Vt   = (unsigned short*)(ws + off); off += (size_t)4 * 24 * 64 * 160 * 2;
  unsigned short* Qb   = (unsigned short*)d_out;  // bf16 scratch; final GEMM overwrites d_out fully

  cvt_all<<<1024, 256, 0, stream>>>(EHS, Wq, Wk, Wv, Wo,
                                    EHSb, Wqb, Wkb, Wvb, Wob);

  gemm_q_kv<<<888, 512, 0, stream>>>(HS, Wqb, Qb, EHSb, Wkb, Wvb, Kb, Vt);

  attn_kernel<<<dim3(64, 24), 256, 0, stream>>>(Qb, Kb, Vt, TMP, Ob);

  gemm_o<<<768, 256, 0, stream>>>(Ob, Wob, (float*)d_out, bo, HS);
}

// Round 23
// 337.810 us; speedup vs baseline: 1.1240x; 1.1240x over previous
//
#include <hip/hip_runtime.h>

typedef __attribute__((ext_vector_type(8))) short short8;
typedef __attribute__((ext_vector_type(4))) float f32x4;
typedef __attribute__((ext_vector_type(4))) unsigned short us4;
typedef __attribute__((ext_vector_type(4))) float float4v;

#define GLB_PTR(p) ((const __attribute__((address_space(1))) void*)(p))
#define LDS_PTR(p) ((__attribute__((address_space(3))) void*)(p))

__device__ __forceinline__ unsigned short f2bf(float f) {
  unsigned int u = __float_as_uint(f);
  u += 0x7FFF + ((u >> 16) & 1);   // round-to-nearest-even
  return (unsigned short)(u >> 16);
}

// ---------------- all fp32 -> bf16 converts, ONE flattened grid-stride range ----------------
__global__ void cvt_all(const float* __restrict__ i0, const float* __restrict__ i1,
                        const float* __restrict__ i2, const float* __restrict__ i3,
                        const float* __restrict__ i4, const float* __restrict__ i5,
                        unsigned short* __restrict__ o0, unsigned short* __restrict__ o1,
                        unsigned short* __restrict__ o2, unsigned short* __restrict__ o3,
                        unsigned short* __restrict__ o4, unsigned short* __restrict__ o5) {
  constexpr int N0 = 16384 * 1536 / 4, N1 = 616 * 1536 / 4, NW = 1536 * 1536 / 4;
  constexpr int TOT = N0 + N1 + 4 * NW;   // 8,887,296 x 4-elem groups
  int i = blockIdx.x * blockDim.x + threadIdx.x;
  const int stride = gridDim.x * blockDim.x;
  for (; i < TOT; i += stride) {
    const float* in; unsigned short* out; int j = i;
    if (j < N0)              { in = i0; out = o0; }
    else if ((j -= N0) < N1) { in = i1; out = o1; }
    else {
      j -= N1;
      const int t = j / NW; j -= t * NW;
      in  = t == 0 ? i2 : t == 1 ? i3 : t == 2 ? i4 : i5;
      out = t == 0 ? o2 : t == 1 ? o3 : t == 2 ? o4 : o5;
    }
    float4v v = *(const float4v*)(in + (size_t)j * 4);
    us4 o;
    o[0] = f2bf(v[0]); o[1] = f2bf(v[1]); o[2] = f2bf(v[2]); o[3] = f2bf(v[3]);
    *(us4*)(out + (size_t)j * 4) = o;
  }
}

// ---------------- big bf16 GEMM body (r18 measured-best total): ----------------
// 256x128 block tile, BK=32, 4 waves (2M x 2N), wave tile 128x64 (acc[8][4]).
// DEPTH-2 48 KB LDS (3 blocks/CU; grid 768 = exact fill), r17 0-conflict swizzle:
// LDS[row][g] holds global granule g^((row>>1)&3), both sides (involution).
// Per iter: vmcnt(6) -> barrier -> frag-reads(12) -> lgkm(0) -> barrier -> stage(kt+2) -> MFMA.
// MODE 0: C bf16.  MODE 1: C fp32 = acc + bias[n] + resid[m,n].
template<int MODE>
__device__ __forceinline__ void gemm_big_body(
    const unsigned short* __restrict__ A,
    const unsigned short* __restrict__ B,
    unsigned short* __restrict__ Cb,
    float* __restrict__ Cf,
    const float* __restrict__ bias,
    const float* __restrict__ resid,
    unsigned short* smem, int bid, int tid) {
  constexpr int K = 1536, N = 1536, BK = 32, NKT = K / BK;  // 48 K-tiles
  unsigned short* As = smem;             // 2 x 256x32 elems
  unsigned short* Bs = smem + 2 * 8192;  // 2 x 128x32 elems

  // XCD-chunked swizzle: 768 blocks -> 96/XCD = 8 m-tiles x 12 n-tiles, n fastest
  const int xcd = bid & 7, idx = bid >> 3;
  const int m0 = (xcd * 8 + idx / 12) * 256;
  const int n0 = (idx % 12) * 128;

  const int w = tid >> 6, l = tid & 63, lr = l & 15, lg = l >> 4;
  const int wr = w >> 1, wc = w & 1;               // 2M x 2N wave grid, wave tile 128x64
  const int ga = lg ^ ((lr >> 1) & 3);             // 0-conflict read granule (r17-verified)

  const int srow = tid >> 2;                       // staging row 0..63 (+i*64 chunks)
  const int sg = (l & 3) ^ ((l >> 3) & 3);         // source granule: g ^ ((row>>1)&3), involution
  const unsigned short* aSrc = A + (size_t)(m0 + srow) * K + sg * 8;
  const unsigned short* bSrc = B + (size_t)(n0 + srow) * K + sg * 8;

  f32x4 acc[8][4] = {};

  auto stage = [&](int buf, int kt) {              // 6 loads/wave
    const int k0 = kt * BK;
    unsigned short* AsW = As + buf * 8192 + w * 512;   // wave-uniform base
    unsigned short* BsW = Bs + buf * 4096 + w * 512;
#pragma unroll
    for (int i = 0; i < 4; ++i)
      __builtin_amdgcn_global_load_lds(GLB_PTR(aSrc + (size_t)(i * 64) * K + k0), LDS_PTR(AsW + i * 2048), 16, 0, 0);
#pragma unroll
    for (int i = 0; i < 2; ++i)
      __builtin_amdgcn_global_load_lds(GLB_PTR(bSrc + (size_t)(i * 64) * K + k0), LDS_PTR(BsW + i * 2048), 16, 0, 0);
  };

  auto loadfrags = [&](int buf, short8* af, short8* bfv) {
    const unsigned short* Asb = As + buf * 8192;
    const unsigned short* Bsb = Bs + buf * 4096;
#pragma unroll
    for (int i = 0; i < 8; ++i)
      af[i] = *(const short8*)(Asb + (wr * 128 + i * 16 + lr) * 32 + ga * 8);
#pragma unroll
    for (int j = 0; j < 4; ++j)
      bfv[j] = *(const short8*)(Bsb + (wc * 64 + j * 16 + lr) * 32 + ga * 8);
  };

  auto mfma_all = [&](short8* af, short8* bfv) {
#pragma unroll
    for (int i = 0; i < 8; ++i)
#pragma unroll
      for (int j = 0; j < 4; ++j)
        acc[i][j] = __builtin_amdgcn_mfma_f32_16x16x32_bf16(af[i], bfv[j], acc[i][j], 0, 0, 0);
  };

  // prologue: 2 K-tiles in flight (12 loads/wave)
  stage(0, 0); stage(1, 1);

  for (int kt = 0; kt < NKT; ++kt) {
    if (kt < NKT - 1) asm volatile("s_waitcnt vmcnt(6)" ::: "memory");  // stage(kt) retired
    else              asm volatile("s_waitcnt vmcnt(0)" ::: "memory");
    __builtin_amdgcn_s_barrier();                       // join: buf kt&1 valid everywhere
    __builtin_amdgcn_sched_barrier(0);
    short8 af[8], bfv[4];
    loadfrags(kt & 1, af, bfv);
    asm volatile("s_waitcnt lgkmcnt(0)" ::: "memory");  // frags in regs
    __builtin_amdgcn_sched_barrier(0);
    __builtin_amdgcn_s_barrier();                       // all waves done reading buf kt&1
    __builtin_amdgcn_sched_barrier(0);
    if (kt + 2 < NKT) stage(kt & 1, kt + 2);            // overwrite freed buffer
    __builtin_amdgcn_s_setprio(1);
    mfma_all(af, bfv);
    __builtin_amdgcn_s_setprio(0);
  }

#pragma unroll
  for (int i = 0; i < 8; ++i) {
    const int rb = m0 + wr * 128 + i * 16 + lg * 4;
#pragma unroll
    for (int j = 0; j < 4; ++j) {
      const int col = n0 + wc * 64 + j * 16 + lr;
#pragma unroll
      for (int r = 0; r < 4; ++r) {
        size_t o = (size_t)(rb + r) * N + col;
        if (MODE == 0) Cb[o] = f2bf(acc[i][j][r]);
        else           Cf[o] = acc[i][j][r] + bias[col] + resid[o];
      }
    }
  }
}

// ---------------- K+V projection body (256 threads) ----------------
// yy<12: Ck row-major bf16.  yy>=12: Vt[c][h][d][e(160)] transposed write (e>=154 junk, masked in attn).
__device__ __forceinline__ void gemm_kv_body(
    const unsigned short* __restrict__ A,    // EHSb [616,1536]
    const unsigned short* __restrict__ Bk,
    const unsigned short* __restrict__ Bv,
    unsigned short* __restrict__ Ck,
    unsigned short* __restrict__ Vt,
    unsigned short* smem, int by, int tid) {
  constexpr int K = 1536, N = 1536, Mc = 615;
  unsigned short* As = smem;
  unsigned short* Bs = smem + 4096;
  const int bx = by % 5, yy = by / 5;
  const unsigned short* B = yy < 12 ? Bk : Bv;
  const int m0 = bx * 128, n0 = (yy % 12) * 128;
  const int t = tid;
  const int w = t >> 6, l = t & 63, lr = l & 15, lg = l >> 4;
  const int wr = w >> 1, wc = w & 1;
  const int srow = t >> 2, scol = (t & 3) * 8;

  f32x4 acc[4][4] = {};
  unsigned short* AsW = As + w * 512;
  unsigned short* BsW = Bs + w * 512;
  long ar0 = m0 + srow;       if (ar0 > Mc) ar0 = Mc;
  long ar1 = m0 + srow + 64;  if (ar1 > Mc) ar1 = Mc;

  for (int k0 = 0; k0 < K; k0 += 32) {
    __builtin_amdgcn_global_load_lds(GLB_PTR(A + ar0 * (long)K + k0 + scol), LDS_PTR(AsW),        16, 0, 0);
    __builtin_amdgcn_global_load_lds(GLB_PTR(A + ar1 * (long)K + k0 + scol), LDS_PTR(AsW + 2048), 16, 0, 0);
    __builtin_amdgcn_global_load_lds(GLB_PTR(B + (long)(n0 + srow) * K + k0 + scol),      LDS_PTR(BsW),        16, 0, 0);
    __builtin_amdgcn_global_load_lds(GLB_PTR(B + (long)(n0 + srow + 64) * K + k0 + scol), LDS_PTR(BsW + 2048), 16, 0, 0);
    __syncthreads();

    short8 af[4], bfv[4];
#pragma unroll
    for (int i = 0; i < 4; ++i) {
      af[i]  = *(const short8*)(As + (wr * 64 + i * 16 + lr) * 32 + lg * 8);
      bfv[i] = *(const short8*)(Bs + (wc * 64 + i * 16 + lr) * 32 + lg * 8);
    }
#pragma unroll
    for (int i = 0; i < 4; ++i)
#pragma unroll
      for (int j = 0; j < 4; ++j)
        acc[i][j] = __builtin_amdgcn_mfma_f32_16x16x32_bf16(af[i], bfv[j], acc[i][j], 0, 0, 0);
    __syncthreads();
  }

  if (yy < 12) {
#pragma unroll
    for (int i = 0; i < 4; ++i) {
      int rb = m0 + wr * 64 + i * 16 + lg * 4;
#pragma unroll
      for (int j = 0; j < 4; ++j) {
        int col = n0 + wc * 64 + j * 16 + lr;
#pragma unroll
        for (int r = 0; r < 4; ++r)
          Ck[(long)(rb + r) * N + col] = f2bf(acc[i][j][r]);
      }
    }
  } else {
#pragma unroll
    for (int i = 0; i < 4; ++i) {
      int rb = m0 + wr * 64 + i * 16 + lg * 4;
#pragma unroll
      for (int j = 0; j < 4; ++j) {
        int col = n0 + wc * 64 + j * 16 + lr;
        int hh = col >> 6, dd = col & 63;
#pragma unroll
        for (int r = 0; r < 4; ++r) {
          int m = rb + r;
          if (m < 616) {
            int c = (unsigned)m / 154u;
            int e = m - c * 154;
            Vt[((long)((c * 24 + hh) * 64 + dd)) * 160 + e] = f2bf(acc[i][j][r]);
          }
        }
      }
    }
  }
}

// ---------------- merged Q-projection + K/V-projection launch ----------------
// blocks 0..767: Q GEMM (exactly one 3-blocks/CU fill); blocks 768..887: K/V projection (tail).
__global__ __launch_bounds__(256, 2) void gemm_q_kv(
    const unsigned short* __restrict__ HSb, const unsigned short* __restrict__ Wqb,
    unsigned short* __restrict__ Qb,
    const unsigned short* __restrict__ EHSb, const unsigned short* __restrict__ Wkb,
    const unsigned short* __restrict__ Wvb,
    unsigned short* __restrict__ Ck, unsigned short* __restrict__ Vt) {
  __shared__ unsigned short smem[24576];   // 49152 B: big path 2x(256+128)x32; kv path 2x 128x32
  if (blockIdx.x < 768)
    gemm_big_body<0>(HSb, Wqb, Qb, nullptr, nullptr, nullptr, smem, blockIdx.x, threadIdx.x);
  else
    gemm_kv_body(EHSb, Wkb, Wvb, Ck, Vt, smem, blockIdx.x - 768, threadIdx.x);
}

// ---------------- O-projection GEMM (MODE 1: + bias + residual, fp32 out) ----------------
__global__ __launch_bounds__(256, 2) void gemm_o(
    const unsigned short* __restrict__ Ob, const unsigned short* __restrict__ Wob,
    float* __restrict__ Cf, const float* __restrict__ bias, const float* __restrict__ resid) {
  __shared__ unsigned short smem[24576];
  gemm_big_body<1>(Ob, Wob, nullptr, Cf, bias, resid, smem, blockIdx.x, threadIdx.x);
}

// ---------------- fused cross-component attention ----------------
// grid (64 s-blocks, 24 heads), 256 thr = 4 waves; wave owns 16 s-rows, all 4 components.
// K/V register double-buffered; softmax WITHOUT max-subtraction (|scores| << 88, fp32-exp safe;
// ratio mathematically identical). P masked to 0 for e>=154. P[w] is WAVE-PRIVATE -> no
// __syncthreads anywhere (DS ops are wave-ordered; lgkm drains only). Output: stage wave's
// 16x64 tile in now-free P[w], then 128B-contiguous short8 stores.
__global__ __launch_bounds__(256) void attn_kernel(
    const unsigned short* __restrict__ Qb,   // [4*4096, 1536]
    const unsigned short* __restrict__ Kb,   // [640, 1536]; rows c*154+e (rows>=616 junk, masked)
    const unsigned short* __restrict__ Vt,   // [4][24][64][160]; e>=154 junk, masked via P
    const float* __restrict__ temp,
    unsigned short* __restrict__ Ob) {       // [4*4096, 1536]
  __shared__ unsigned short P[4][4][16][160];  // [wave][c][s][e] bf16 weights (wave-private)
  const int h = blockIdx.y, sb = blockIdx.x;
  const int t = threadIdx.x, w = t >> 6, l = t & 63, lr = l & 15, lg = l >> 4;
  const int s0 = sb * 64 + w * 16;
  const float sc = 1.0f / (temp[0] + 1e-8f);

  short8 qf[4][2];
#pragma unroll
  for (int c = 0; c < 4; ++c)
#pragma unroll
    for (int kt = 0; kt < 2; ++kt)
      qf[c][kt] = *(const short8*)(Qb + (long)(c * 4096 + s0 + lr) * 1536 + h * 64 + kt * 32 + lg * 8);

  short8 kA[4][2], kB[4][2];
  auto loadK = [&](int et, short8 (&k)[4][2]) {
#pragma unroll
    for (int c = 0; c < 4; ++c)
#pragma unroll
      for (int kt = 0; kt < 2; ++kt)
        k[c][kt] = *(const short8*)(Kb + (long)(c * 154 + et * 16 + lr) * 1536 + h * 64 + kt * 32 + lg * 8);
  };

  auto qk_step = [&](int et, short8 (&kc)[4][2], short8 (&kn)[4][2], bool pre) {
    if (pre) loadK(et + 1, kn);               // issue next-tile loads BEFORE dependent MFMAs
    f32x4 sa[4] = {};
#pragma unroll
    for (int c = 0; c < 4; ++c)
#pragma unroll
      for (int kt = 0; kt < 2; ++kt)
        sa[c] = __builtin_amdgcn_mfma_f32_16x16x32_bf16(kc[c][kt], qf[c][kt], sa[c], 0, 0, 0);
    float wv[4][4];
#pragma unroll
    for (int r = 0; r < 4; ++r) {
      float e0 = __expf(sa[0][r] * sc), e1 = __expf(sa[1][r] * sc);
      float e2 = __expf(sa[2][r] * sc), e3 = __expf(sa[3][r] * sc);
      float inv = 1.0f / (e0 + e1 + e2 + e3);
      wv[0][r] = e0 * inv; wv[1][r] = e1 * inv; wv[2][r] = e2 * inv; wv[3][r] = e3 * inv;
    }
#pragma unroll
    for (int c = 0; c < 4; ++c) {
      us4 pk;
#pragma unroll
      for (int r = 0; r < 4; ++r)
        pk[r] = (et * 16 + lg * 4 + r < 154) ? f2bf(wv[c][r]) : (unsigned short)0;
      *(us4*)&P[w][c][lr][et * 16 + lg * 4] = pk;
    }
  };

  loadK(0, kA);
#pragma unroll
  for (int et = 0; et < 10; et += 2) {
    qk_step(et,     kA, kB, true);
    qk_step(et + 1, kB, kA, et + 1 < 9);
  }
  asm volatile("s_waitcnt lgkmcnt(0)" ::: "memory");   // P writes drained (wave-private, no bar)
  __builtin_amdgcn_sched_barrier(0);

  // ---- PV with V-fragment register double-buffer ----
  short8 vA[4], vB[4];
  auto loadV = [&](int c, int ks, short8 (&v)[4]) {
#pragma unroll
    for (int nt = 0; nt < 4; ++nt)
      v[nt] = *(const short8*)(Vt + (long)((c * 24 + h) * 64 + nt * 16 + lr) * 160 + ks * 32 + lg * 8);
  };

  f32x4 o[4][4] = {};
  loadV(0, 0, vA);
#pragma unroll
  for (int p = 0; p < 10; ++p) {
    const int i0 = 2 * p, i1 = 2 * p + 1;
    const int c0 = i0 / 5, k0 = i0 % 5;
    const int c1 = i1 / 5, k1 = i1 % 5;
    loadV(c1, k1, vB);                        // prefetch odd step's V
    short8 pf0 = *(const short8*)&P[w][c0][lr][k0 * 32 + lg * 8];
#pragma unroll
    for (int nt = 0; nt < 4; ++nt)
      o[c0][nt] = __builtin_amdgcn_mfma_f32_16x16x32_bf16(pf0, vA[nt], o[c0][nt], 0, 0, 0);
    if (p < 9) loadV((i1 + 1) / 5, (i1 + 1) % 5, vA);   // prefetch next even step's V
    short8 pf1 = *(const short8*)&P[w][c1][lr][k1 * 32 + lg * 8];
#pragma unroll
    for (int nt = 0; nt < 4; ++nt)
      o[c1][nt] = __builtin_amdgcn_mfma_f32_16x16x32_bf16(pf1, vB[nt], o[c1][nt], 0, 0, 0);
  }

  // ---- coalesced Ob write: stage 16x64 tile in now-free wave-private P[w], 128B chunks ----
  unsigned short* OS = &P[w][0][0][0];        // PV's P reads all retired (consumed by MFMAs)
#pragma unroll
  for (int c = 0; c < 4; ++c) {
#pragma unroll
    for (int nt = 0; nt < 4; ++nt)
#pragma unroll
      for (int r = 0; r < 4; ++r)
        OS[(lg * 4 + r) * 64 + nt * 16 + lr] = f2bf(o[c][nt][r]);
    asm volatile("s_waitcnt lgkmcnt(0)" ::: "memory");  // scalar ds_writes drained
    __builtin_amdgcn_sched_barrier(0);
#pragma unroll
    for (int p = 0; p < 2; ++p) {
      const int flat = p * 512 + l * 8;       // elem index within 16x64 tile
      const int row = flat >> 6, col = flat & 63;
      short8 v = *(const short8*)(OS + flat);
      *(short8*)(Ob + (long)(c * 4096 + s0 + row) * 1536 + h * 64 + col) = v;
    }
  }
}

extern "C" void kernel_launch(void* const* d_in, const int* in_sizes, int n_in,
                              void* d_out, int out_size, void* d_ws, size_t ws_size,
                              hipStream_t stream) {
  (void)in_sizes; (void)n_in; (void)out_size; (void)ws_size;
  const float* HS  = (const float*)d_in[0];
  const float* EHS = (const float*)d_in[1];
  const float* TMP = (const float*)d_in[2];
  const float* Wq  = (const float*)d_in[3];
  const float* Wk  = (const float*)d_in[4];
  const float* Wv  = (const float*)d_in[5];
  const float* Wo  = (const float*)d_in[6];
  const float* bo  = (const float*)d_in[7];

  char* ws = (char*)d_ws;
  size_t off = 0;
  unsigned short* HSb  = (unsigned short*)(ws + off); off += (size_t)16384 * 1536 * 2;  // reused as Ob
  unsigned short* Ob   = HSb;
  unsigned short* EHSb = (unsigned short*)(ws + off); off += (size_t)616 * 1536 * 2;
  unsigned short* Wqb  = (unsigned short*)(ws + off); off += (size_t)1536 * 1536 * 2;
  unsigned short* Wkb  = (unsigned short*)(ws + off); off += (size_t)1536 * 1536 * 2;
  unsigned short* Wvb  = (unsigned short*)(ws + off); off += (size_t)1536 * 1536 * 2;
  unsigned short* Wob  = (unsigned short*)(ws + off); off += (size_t)1536 * 1536 * 2;
  unsigned short* Kb   = (unsigned short*)(ws + off); off += (size_t)640 * 1536 * 2;
  unsigned short* Vt   = (unsigned short*)(ws + off); off += (size_t)4 * 24 * 64 * 160 * 2;
  unsigned short* Qb   = (unsigned short*)d_out;  // bf16 scratch; final GEMM overwrites d_out fully

  cvt_all<<<2048, 256, 0, stream>>>(HS, EHS, Wq, Wk, Wv, Wo,
                                    HSb, EHSb, Wqb, Wkb, Wvb, Wob);

  gemm_q_kv<<<888, 256, 0, stream>>>(HSb, Wqb, Qb, EHSb, Wkb, Wvb, Kb, Vt);

  attn_kernel<<<dim3(64, 24), 256, 0, stream>>>(Qb, Kb, Vt, TMP, Ob);

  gemm_o<<<768, 256, 0, stream>>>(Ob, Wob, (float*)d_out, bo, HS);
}